// Round 8
// baseline (120.015 us; speedup 1.0000x reference)
//
#include <hip/hip_runtime.h>
#include <hip/hip_fp16.h>

// Depthwise 3D Gaussian conv (1,3,160,160,160) fp32, K=25, radius=12.
// Separable. Round 8: fuse W+H (both are within-(c,d)-plane!) into one
// kernel; LDS holds ONLY the W-output tile (fp16, 33.7 KB -> 4 blocks/CU).
// W phase reads global directly with clamped unconditional float4 loads +
// branchless masking (no divergent alloca -> no scratch spill, the r3/r4
// disease). D pass unchanged from r7.

#define NV 160
constexpr int KS    = 25;
constexpr int RAD   = 12;
constexpr int PLANE = NV * NV;        // 25600
constexpr int VOL   = NV * NV * NV;   // 4,096,000
constexpr int TOT   = 3 * VOL;        // 12,288,000

// fused_wh geometry
constexpr int HHALF  = 80;            // h-half per block
constexpr int WROWS  = 104;           // 80 + 2*12 W-output rows in LDS
constexpr int WPITCH = 81;            // half2 per row (80 + 1 pad)
constexpr int WTASKS = WROWS * 20;    // 2080 (20 segs of 8 w)

// conv_d geometry (r7, proven)
constexpr int ROWS  = NV + 2 * RAD;   // 184
constexpr int QP    = 9;              // float4 pitch (8 quads + pad)
constexpr int OPT4  = 5;
constexpr int WIN4  = OPT4 + KS - 1;  // 29

__device__ __forceinline__ void pk(float2& a, float2 g, float2 v) {
    asm("v_pk_fma_f32 %0, %1, %2, %0" : "+v"(a) : "v"(g), "v"(v));
}

// Recover g1[t] from k3: g1[t] = g3[t,12,12] / cbrt(g3[12,12,12])^2 (exact).
__device__ __forceinline__ void load_g(const float* __restrict__ k3, float* g) {
    float c   = k3[12 * 625 + 312];          // g1[12]^3
    float g12 = cbrtf(c);
    float inv = 1.0f / (g12 * g12);
#pragma unroll
    for (int t = 0; t < KS; ++t) g[t] = k3[t * 625 + 312] * inv;
}

// ---------------- fused W+H pass (per (c,d)-plane h-half) ----------------
__global__ __launch_bounds__(320, 4) void fused_wh(const float* __restrict__ in,
                                                   __half* __restrict__ out,
                                                   const float* __restrict__ k3) {
    __shared__ __half2 WH[WROWS][WPITCH];    // 104*81*4 = 33696 B
    float g[KS];
    load_g(k3, g);

    int tid  = threadIdx.x;
    int b    = blockIdx.x;
    int half = b & 1;
    int cd   = b >> 1;                 // c*160 + d
    int h0   = half * HHALF;
    const float* base = in + (size_t)cd * PLANE;

    // ---- phase W: 2080 tasks = (row r 0..103) x (seg s 0..19, 8 w each) ----
#pragma unroll
    for (int itr = 0; itr < 7; ++itr) {
        int task = itr * 320 + tid;
        if (task < WTASKS) {
            int r  = task % WROWS;
            int s  = task / WROWS;     // 0..19
            int hq = h0 + r - RAD;     // source h row for this W-output row
            if (hq >= 0 && hq < NV) {
                const float* rp = base + hq * NV;
                int w0 = 8 * s - RAD;  // multiple of 4
                float buf[32];
#pragma unroll
                for (int u = 0; u < 8; ++u) {
                    int wa = w0 + 4 * u;
                    int wc = wa < 0 ? 0 : (wa > NV - 4 ? NV - 4 : wa);
                    float4 f = *(const float4*)(rp + wc);
                    buf[4*u]   = f.x; buf[4*u+1] = f.y;
                    buf[4*u+2] = f.z; buf[4*u+3] = f.w;
                }
                // branchless boundary mask (clamped quads are fully OOB)
#pragma unroll
                for (int m = 0; m < 32; ++m) {
                    int w = w0 + m;
                    buf[m] = (w >= 0 && w < NV) ? buf[m] : 0.f;
                }
                float acc[8];
#pragma unroll
                for (int k = 0; k < 8; ++k) acc[k] = 0.f;
#pragma unroll
                for (int t = 0; t < KS; ++t)
#pragma unroll
                    for (int k = 0; k < 8; ++k)
                        acc[k] = fmaf(g[t], buf[k + t], acc[k]);
#pragma unroll
                for (int u = 0; u < 4; ++u)
                    WH[r][4*s + u] =
                        __float22half2_rn(make_float2(acc[2*u], acc[2*u+1]));
            } else {
                __half2 z = __float22half2_rn(make_float2(0.f, 0.f));
#pragma unroll
                for (int u = 0; u < 4; ++u) WH[r][4*s + u] = z;
            }
        }
    }
    __syncthreads();

    // ---- phase H: wp = w-pair 0..79, hg = 0..3, 2 chunks x 10 rows ----
    int wp = tid % 80;
    int hg = tid / 80;
    float2 g2[KS];
#pragma unroll
    for (int t = 0; t < KS; ++t) g2[t] = make_float2(g[t], g[t]);

#pragma unroll
    for (int ch = 0; ch < 2; ++ch) {
        int hb = hg * 20 + ch * 10;    // output row base within half (0..70)
        float2 acc[10];
#pragma unroll
        for (int j = 0; j < 10; ++j) acc[j] = make_float2(0.f, 0.f);
#pragma unroll
        for (int it = 0; it < 34; ++it) {
            float2 v = __half22float2(WH[hb + it][wp]);
#pragma unroll
            for (int j = 0; j < 10; ++j) {
                int t = it - j;
                if (t >= 0 && t < KS) pk(acc[j], g2[t], v);
            }
        }
        __half* ob = out + (size_t)cd * PLANE + (size_t)(h0 + hb) * NV + 2 * wp;
#pragma unroll
        for (int j = 0; j < 10; ++j)
            *(__half2*)(ob + j * NV) = __float22half2_rn(acc[j]);
    }
}

// ---------------- D pass: f16 in -> f32 out (r7, proven) ----------------
__global__ __launch_bounds__(256) void conv_d(const __half* __restrict__ in,
                                              float* __restrict__ out,
                                              const float* __restrict__ k3) {
    __shared__ float4 T4[ROWS][QP];
    float gs[KS];
    load_g(k3, gs);
    float2 g2[KS];
#pragma unroll
    for (int t = 0; t < KS; ++t) g2[t] = make_float2(gs[t], gs[t]);

    int tid = threadIdx.x;
    int b   = blockIdx.x;
    int wt  = b % 5;
    int ch  = b / 5;               // c*160 + h
    int c   = ch / NV, h = ch % NV;
    int w0  = wt * 32;
    const __half* base = in + (size_t)c * VOL + h * NV + w0;

    int q = tid & 7, r = tid >> 3;
#pragma unroll
    for (int ib = 0; ib < ROWS; ib += 32) {
        int i = ib + r;
        if (i < ROWS) {
            int d = i - RAD;
            float4 v = make_float4(0.f, 0.f, 0.f, 0.f);
            if (d >= 0 && d < NV) {
                const __half2* p2 = (const __half2*)(base + (size_t)d * PLANE + 4 * q);
                float2 lo = __half22float2(p2[0]);
                float2 hi = __half22float2(p2[1]);
                v = make_float4(lo.x, lo.y, hi.x, hi.y);
            }
            T4[i][q] = v;
        }
    }
    __syncthreads();

    int wq = tid & 7, ct = tid >> 3;
    int db = ct * OPT4;
    float2 alo[OPT4], ahi[OPT4];
#pragma unroll
    for (int j = 0; j < OPT4; ++j) { alo[j] = make_float2(0.f, 0.f); ahi[j] = alo[j]; }
#pragma unroll
    for (int it = 0; it < WIN4; ++it) {
        float4 v = T4[db + it][wq];
        float2 vlo = make_float2(v.x, v.y);
        float2 vhi = make_float2(v.z, v.w);
#pragma unroll
        for (int j = 0; j < OPT4; ++j) {
            int t = it - j;
            if (t >= 0 && t < KS) { pk(alo[j], g2[t], vlo); pk(ahi[j], g2[t], vhi); }
        }
    }
    float* ob = out + (size_t)c * VOL + h * NV + w0 + 4 * wq;
#pragma unroll
    for (int j = 0; j < OPT4; ++j)
        *(float4*)(ob + (size_t)(db + j) * PLANE) =
            make_float4(alo[j].x, alo[j].y, ahi[j].x, ahi[j].y);
}

// Fallback (only if ws too small): direct 25^3-tap depthwise conv.
__global__ __launch_bounds__(256) void conv3d_direct(const float* __restrict__ x,
                                                     const float* __restrict__ k3,
                                                     float* __restrict__ out) {
    int idx = blockIdx.x * 256 + threadIdx.x;
    if (idx >= TOT) return;
    int w = idx % NV;
    int t = idx / NV;
    int h = t % NV; t /= NV;
    int d = t % NV;
    int c = t / NV;
    const float* kc = k3 + c * (KS * KS * KS);
    float acc = 0.f;
    for (int i = 0; i < KS; ++i) {
        int dd = d + i - RAD;
        if (dd < 0 || dd >= NV) continue;
        for (int j = 0; j < KS; ++j) {
            int hh = h + j - RAD;
            if (hh < 0 || hh >= NV) continue;
            const float* xr = x + (c * NV + dd) * NV * NV + hh * NV + (w - RAD);
            const float* kr = kc + (i * KS + j) * KS;
            int k0 = (RAD - w) > 0 ? (RAD - w) : 0;
            int k1 = (NV + RAD - w) < KS ? (NV + RAD - w) : KS;
            for (int k = k0; k < k1; ++k) acc += kr[k] * xr[k];
        }
    }
    out[idx] = acc;
}

extern "C" void kernel_launch(void* const* d_in, const int* in_sizes, int n_in,
                              void* d_out, int out_size, void* d_ws, size_t ws_size,
                              hipStream_t stream) {
    const float* x  = (const float*)d_in[0];
    const float* k3 = (const float*)d_in[1];
    float* out = (float*)d_out;

    if (ws_size >= (size_t)TOT * sizeof(__half)) {
        __half* tmpA = (__half*)d_ws;
        fused_wh<<<960, 320, 0, stream>>>(x, tmpA, k3);   // x -> tmpA (W+H, f16)
        conv_d<<<2400, 256, 0, stream>>>(tmpA, out, k3);  // tmpA -> out (D, f32)
    } else {
        conv3d_direct<<<(TOT + 255) / 256, 256, 0, stream>>>(x, k3, out);
    }
}

// Round 9
// 57.033 us; speedup vs baseline: 2.1043x; 2.1043x over previous
//
#include <hip/hip_runtime.h>
#include <hip/hip_fp16.h>

// Depthwise 3D Gaussian conv (1,3,160,160,160) fp32, K=25, radius=12.
// Separable -> three 1-D passes (r7 structure, fp16 intermediates).
// Round 9: 16B staging loads for H/D passes; LDS-transposed coalesced
// store epilogue for W pass (its direct stores were 4B row-scattered).

#define NV 160
constexpr int KS    = 25;
constexpr int RAD   = 12;
constexpr int PLANE = NV * NV;        // 25600
constexpr int VOL   = NV * NV * NV;   // 4,096,000
constexpr int TOT   = 3 * VOL;        // 12,288,000
constexpr int ROWS  = NV + 2 * RAD;   // 184

// W-pass geometry
constexpr int PITCH = 17;             // float2 pitch
constexpr int OPT   = 10;
constexpr int WIN   = OPT + KS - 1;   // 34
constexpr int OROW  = 168;            // output-staging row pitch (halfs, 336B)

// H/D-pass geometry (float4 tiles)
constexpr int QP    = 9;              // float4 pitch (8 quads + pad)
constexpr int OPT4  = 5;              // quad-outputs per thread
constexpr int WIN4  = OPT4 + KS - 1;  // 29

__device__ __forceinline__ void pk(float2& a, float2 g, float2 v) {
    asm("v_pk_fma_f32 %0, %1, %2, %0" : "+v"(a) : "v"(g), "v"(v));
}

// Recover g1[t] from k3: g1[t] = g3[t,12,12] / cbrt(g3[12,12,12])^2 (exact).
__device__ __forceinline__ void load_g(const float* __restrict__ k3, float* g) {
    float c   = k3[12 * 625 + 312];          // g1[12]^3
    float g12 = cbrtf(c);
    float inv = 1.0f / (g12 * g12);
#pragma unroll
    for (int t = 0; t < KS; ++t) g[t] = k3[t * 625 + 312] * inv;
}

// unpack 8 halfs (uint4) -> two float4
__device__ __forceinline__ void unpack8(uint4 raw, float4& lo, float4& hi) {
    __half2* hp = (__half2*)&raw;
    float2 a = __half22float2(hp[0]);
    float2 b = __half22float2(hp[1]);
    float2 c = __half22float2(hp[2]);
    float2 d = __half22float2(hp[3]);
    lo = make_float4(a.x, a.y, b.x, b.y);
    hi = make_float4(c.x, c.y, d.x, d.y);
}

// ---------------- W pass: f32 in -> f16 out ----------------
__global__ __launch_bounds__(256) void conv_w(const float* __restrict__ in,
                                              __half* __restrict__ out,
                                              const float* __restrict__ k3) {
    __shared__ float2 T[ROWS][PITCH];        // 25024 B (reused as out-stage)
    float gs[KS];
    load_g(k3, gs);
    float2 g2[KS];
#pragma unroll
    for (int t = 0; t < KS; ++t) g2[t] = make_float2(gs[t], gs[t]);

    int tid = threadIdx.x;
    int b   = blockIdx.x;
    int ht  = b % 5;
    int cd  = b / 5;               // c*160 + d
    int h0  = ht * 32;
    const float* base = in + (size_t)cd * PLANE;

    // stage transposed: T[wi][hp] = {x[h0+2hp][wi-12], x[h0+2hp+1][wi-12]}
    int wl = tid & 31, hq = tid >> 5;        // wl 0..31, hq 0..7
#pragma unroll
    for (int hh = 0; hh < 2; ++hh) {
        int hp = hq + hh * 8;                // 0..15
        const float* r0 = base + (h0 + 2 * hp) * NV;
#pragma unroll
        for (int ib = 0; ib < ROWS; ib += 32) {
            int i = ib + wl;
            if (i < ROWS) {
                int wv = i - RAD;
                float a = 0.f, bb = 0.f;
                if (wv >= 0 && wv < NV) { a = r0[wv]; bb = r0[NV + wv]; }
                T[i][hp] = make_float2(a, bb);
            }
        }
    }
    __syncthreads();

    int p  = tid & 15;             // h-pair
    int ct = tid >> 4;             // 0..15
    int wb = ct * OPT;
    float2 acc[OPT];
#pragma unroll
    for (int j = 0; j < OPT; ++j) acc[j] = make_float2(0.f, 0.f);
#pragma unroll
    for (int it = 0; it < WIN; ++it) {
        float2 v = T[wb + it][p];
#pragma unroll
        for (int j = 0; j < OPT; ++j) {
            int t = it - j;
            if (t >= 0 && t < KS) pk(acc[j], g2[t], v);
        }
    }

    // coalesced store epilogue: stage 32x160 halfs (pitch 168) in LDS
    __syncthreads();
    __half* Ost = (__half*)(&T[0][0]);       // 32*336 = 10752 B <= 25024
#pragma unroll
    for (int j = 0; j < OPT; ++j) {
        Ost[(2 * p)     * OROW + wb + j] = __float2half_rn(acc[j].x);
        Ost[(2 * p + 1) * OROW + wb + j] = __float2half_rn(acc[j].y);
    }
    __syncthreads();
    __half* ob = out + (size_t)cd * PLANE + (size_t)h0 * NV;
#pragma unroll
    for (int it = 0; it < 3; ++it) {
        int task = it * 256 + tid;           // 640 = 32 rows x 20 chunks
        if (task < 640) {
            int chunk = task % 20, row = task / 20;
            uint4 v = *(const uint4*)(Ost + row * OROW + 8 * chunk);
            *(uint4*)(ob + (size_t)row * NV + 8 * chunk) = v;
        }
    }
}

// ---------------- H pass: f16 in -> f16 out ----------------
__global__ __launch_bounds__(256) void conv_h(const __half* __restrict__ in,
                                              __half* __restrict__ out,
                                              const float* __restrict__ k3) {
    __shared__ float4 T4[ROWS][QP];
    float gs[KS];
    load_g(k3, gs);
    float2 g2[KS];
#pragma unroll
    for (int t = 0; t < KS; ++t) g2[t] = make_float2(gs[t], gs[t]);

    int tid = threadIdx.x;
    int b   = blockIdx.x;
    int wt  = b % 5;
    int cd  = b / 5;               // c*160 + d
    int w0  = wt * 32;
    const __half* base = in + (size_t)cd * PLANE + w0;

    // stage: 16B loads, e = 16B-eighth (8 halfs), r0 = row within sweep
    int e = tid & 3, r0 = tid >> 2;          // e 0..3, r0 0..63
#pragma unroll
    for (int ib = 0; ib < ROWS; ib += 64) {
        int i = ib + r0;
        if (i < ROWS) {
            int h = i - RAD;
            float4 lo = make_float4(0.f, 0.f, 0.f, 0.f), hi = lo;
            if (h >= 0 && h < NV) {
                uint4 raw = *(const uint4*)(base + h * NV + 8 * e);
                unpack8(raw, lo, hi);
            }
            T4[i][2 * e]     = lo;
            T4[i][2 * e + 1] = hi;
        }
    }
    __syncthreads();

    int wq = tid & 7, ct = tid >> 3;         // ct 0..31
    int hb = ct * OPT4;
    float2 alo[OPT4], ahi[OPT4];
#pragma unroll
    for (int j = 0; j < OPT4; ++j) { alo[j] = make_float2(0.f, 0.f); ahi[j] = alo[j]; }
#pragma unroll
    for (int it = 0; it < WIN4; ++it) {
        float4 v = T4[hb + it][wq];
        float2 vlo = make_float2(v.x, v.y);
        float2 vhi = make_float2(v.z, v.w);
#pragma unroll
        for (int j = 0; j < OPT4; ++j) {
            int t = it - j;
            if (t >= 0 && t < KS) { pk(alo[j], g2[t], vlo); pk(ahi[j], g2[t], vhi); }
        }
    }
    __half* ob = out + (size_t)cd * PLANE + w0 + 4 * wq;
#pragma unroll
    for (int j = 0; j < OPT4; ++j) {
        __half2 o01 = __float22half2_rn(make_float2(alo[j].x, alo[j].y));
        __half2 o23 = __float22half2_rn(make_float2(ahi[j].x, ahi[j].y));
        __half* pdst = ob + (hb + j) * NV;
        *(__half2*)(pdst)     = o01;
        *(__half2*)(pdst + 2) = o23;
    }
}

// ---------------- D pass: f16 in -> f32 out ----------------
__global__ __launch_bounds__(256) void conv_d(const __half* __restrict__ in,
                                              float* __restrict__ out,
                                              const float* __restrict__ k3) {
    __shared__ float4 T4[ROWS][QP];
    float gs[KS];
    load_g(k3, gs);
    float2 g2[KS];
#pragma unroll
    for (int t = 0; t < KS; ++t) g2[t] = make_float2(gs[t], gs[t]);

    int tid = threadIdx.x;
    int b   = blockIdx.x;
    int wt  = b % 5;
    int ch  = b / 5;               // c*160 + h
    int c   = ch / NV, h = ch % NV;
    int w0  = wt * 32;
    const __half* base = in + (size_t)c * VOL + h * NV + w0;

    int e = tid & 3, r0 = tid >> 2;
#pragma unroll
    for (int ib = 0; ib < ROWS; ib += 64) {
        int i = ib + r0;
        if (i < ROWS) {
            int d = i - RAD;
            float4 lo = make_float4(0.f, 0.f, 0.f, 0.f), hi = lo;
            if (d >= 0 && d < NV) {
                uint4 raw = *(const uint4*)(base + (size_t)d * PLANE + 8 * e);
                unpack8(raw, lo, hi);
            }
            T4[i][2 * e]     = lo;
            T4[i][2 * e + 1] = hi;
        }
    }
    __syncthreads();

    int wq = tid & 7, ct = tid >> 3;
    int db = ct * OPT4;
    float2 alo[OPT4], ahi[OPT4];
#pragma unroll
    for (int j = 0; j < OPT4; ++j) { alo[j] = make_float2(0.f, 0.f); ahi[j] = alo[j]; }
#pragma unroll
    for (int it = 0; it < WIN4; ++it) {
        float4 v = T4[db + it][wq];
        float2 vlo = make_float2(v.x, v.y);
        float2 vhi = make_float2(v.z, v.w);
#pragma unroll
        for (int j = 0; j < OPT4; ++j) {
            int t = it - j;
            if (t >= 0 && t < KS) { pk(alo[j], g2[t], vlo); pk(ahi[j], g2[t], vhi); }
        }
    }
    float* ob = out + (size_t)c * VOL + h * NV + w0 + 4 * wq;
#pragma unroll
    for (int j = 0; j < OPT4; ++j)
        *(float4*)(ob + (size_t)(db + j) * PLANE) =
            make_float4(alo[j].x, alo[j].y, ahi[j].x, ahi[j].y);
}

// Fallback (only if ws too small): direct 25^3-tap depthwise conv.
__global__ __launch_bounds__(256) void conv3d_direct(const float* __restrict__ x,
                                                     const float* __restrict__ k3,
                                                     float* __restrict__ out) {
    int idx = blockIdx.x * 256 + threadIdx.x;
    if (idx >= TOT) return;
    int w = idx % NV;
    int t = idx / NV;
    int h = t % NV; t /= NV;
    int d = t % NV;
    int c = t / NV;
    const float* kc = k3 + c * (KS * KS * KS);
    float acc = 0.f;
    for (int i = 0; i < KS; ++i) {
        int dd = d + i - RAD;
        if (dd < 0 || dd >= NV) continue;
        for (int j = 0; j < KS; ++j) {
            int hh = h + j - RAD;
            if (hh < 0 || hh >= NV) continue;
            const float* xr = x + (c * NV + dd) * NV * NV + hh * NV + (w - RAD);
            const float* kr = kc + (i * KS + j) * KS;
            int k0 = (RAD - w) > 0 ? (RAD - w) : 0;
            int k1 = (NV + RAD - w) < KS ? (NV + RAD - w) : KS;
            for (int k = k0; k < k1; ++k) acc += kr[k] * xr[k];
        }
    }
    out[idx] = acc;
}

extern "C" void kernel_launch(void* const* d_in, const int* in_sizes, int n_in,
                              void* d_out, int out_size, void* d_ws, size_t ws_size,
                              hipStream_t stream) {
    const float* x  = (const float*)d_in[0];
    const float* k3 = (const float*)d_in[1];
    float* out = (float*)d_out;

    if (ws_size >= (size_t)TOT * 2 * sizeof(__half)) {
        __half* tmpA = (__half*)d_ws;
        __half* tmpB = tmpA + TOT;
        conv_w<<<2400, 256, 0, stream>>>(x, tmpA, k3);     // f32 -> f16 (W)
        conv_h<<<2400, 256, 0, stream>>>(tmpA, tmpB, k3);  // f16 -> f16 (H)
        conv_d<<<2400, 256, 0, stream>>>(tmpB, out, k3);   // f16 -> f32 (D)
    } else {
        conv3d_direct<<<(TOT + 255) / 256, 256, 0, stream>>>(x, k3, out);
    }
}